// Round 7
// baseline (476.417 us; speedup 1.0000x reference)
//
#include <hip/hip_runtime.h>

// Attention_37074157699274 : fused qkv-proj + 8-head attention (n=32,d=64) + out-proj
// R3: fragment-packed weights, dist-2 weight prefetch, nt x-streaming.
// R4-R7: LDS 74240->49152 (Xs/Os overlay pool, vT [64][32]+swz, qs/ks [32][64]+swz).
// R10: occupancy was NEVER LDS-bound. Occupancy 22.7% constant across LDS
//   74240/53248/49152 => pin is unified VGPR+AGPR total (~192/wave -> 2 waves/SIMD;
//   waves = floor(512/total)). R5 proved it: forced (256,3) hit 32% occupancy
//   (arch 84 + acc ~84 = 168 <= 170) but spilled ~35 regs (structure needed ~250).
//   Fix: cut structural pressure ~64 regs — bb[2][8]/wb[2][8] double-buffers ->
//   ping-pong half-buffers bbA/bbB, wbA/wbB (4 frags each). Peak ~135 total.
//   Re-apply __launch_bounds__(256,3): total <=170 -> 3 waves/SIMD, no spill.
//   No-spill check: WRITE_SIZE must stay ~139MB (R5 spill showed 972MB).

typedef __bf16 bf16x8 __attribute__((ext_vector_type(8)));
typedef __bf16 bf16x4 __attribute__((ext_vector_type(4)));
typedef float f32x4 __attribute__((ext_vector_type(4)));
typedef float f32x4v __attribute__((ext_vector_type(4)));

__device__ __forceinline__ f32x4 mfma16(bf16x8 a, bf16x8 b, f32x4 c) {
  return __builtin_amdgcn_mfma_f32_16x16x32_bf16(a, b, c, 0, 0, 0);
}

// ws: [0,786432) WqkvP bf16 packed frags ; [786432,1048576) WoutP bf16 packed frags
// WqkvP: frag t = (combo*8 + kk)*64 + lane, combo = (mat*8+h)*4+nt, 8 ele each:
//   ele j = Wqkv[k][n], n = mat*512+h*64+nt*16+(lane&15), k = kk*32+(lane>>4)*8+j
// WoutP: frag t = (ntile*16 + kk)*64 + lane:
//   ele j = Wout[k][n], n = ntile*16+(lane&15), k = kk*32+(lane>>4)*8+j
__global__ __launch_bounds__(256) void prep_weights(const float* __restrict__ Wqkv,
                                                    const float* __restrict__ Wout,
                                                    __bf16* __restrict__ WqkvP,
                                                    __bf16* __restrict__ WoutP) {
  int t = blockIdx.x * 256 + threadIdx.x;
  if (t < 49152) {
    int lane = t & 63, rest = t >> 6;
    int kk = rest & 7, combo = rest >> 3;
    int nt = combo & 3, mh = combo >> 2;
    int h = mh & 7, mat = mh >> 3;
    int l16 = lane & 15, quad = lane >> 4;
    int n = mat * 512 + h * 64 + nt * 16 + l16;
    int k0 = kk * 32 + quad * 8;
    __bf16* dst = WqkvP + (size_t)t * 8;
#pragma unroll
    for (int j = 0; j < 8; j++) dst[j] = (__bf16)Wqkv[(size_t)(k0 + j) * 1536 + n];
  }
  int t2 = t - 49152;
  if (t2 >= 0 && t2 < 16384) {
    int lane = t2 & 63, rest = t2 >> 6;
    int kk = rest & 15, ntile = rest >> 4;
    int l16 = lane & 15, quad = lane >> 4;
    int n = ntile * 16 + l16;
    int k0 = kk * 32 + quad * 8;
    __bf16* dst = WoutP + (size_t)t2 * 8;
#pragma unroll
    for (int j = 0; j < 8; j++) dst[j] = (__bf16)Wout[(size_t)(k0 + j) * 256 + n];
  }
}

__global__ __launch_bounds__(256, 3) void attn_fused(const float* __restrict__ x,
                                                     const __bf16* __restrict__ WqkvP,
                                                     const __bf16* __restrict__ WoutP,
                                                     const float* __restrict__ b_out,
                                                     float* __restrict__ out) {
  // Single pool, 49152 B (3 blocks/CU: 147456 <= 163840; regs are the other gate).
  // Phase A (staging):   Xs overlay [32][264] = 8448 ele
  // Phase B (attention): per-wave {qs[32][64] swz, ks[32][64] swz, vT[64][32] swz} = 6144 ele
  // Phase C (out-proj):  Os overlay [32][520] = 16640 ele
  __shared__ __align__(16) __bf16 pool[4 * 6144];

  const int tid  = threadIdx.x;
  const int wave = tid >> 6;
  const int lane = tid & 63;
  const int quad = lane >> 4;
  const int l16  = lane & 15;
  const int bp   = blockIdx.x;

  __bf16* qs = pool + wave * 6144;  // [32][64] swizzled (reused as P scratch)
  __bf16* ks = qs + 2048;           // [32][64] swizzled
  __bf16* vT = ks + 2048;           // [64][32] v transposed, XOR-swizzled
  __bf16* Xs = pool;                // [32][264] staging overlay (dead after hoist)
  __bf16* Os = pool;                // [32][520] after barrier 2 (overlays pool)

  // ---- stage X tile -> LDS bf16 (non-temporal: read-once stream) ----
  const f32x4v* xg = (const f32x4v*)(x + (size_t)bp * 32 * 256);
  for (int i = tid; i < 32 * 64; i += 256) {
    int row = i >> 6, c4 = i & 63;
    f32x4v v = __builtin_nontemporal_load(xg + i);
    bf16x4 pk;
    pk[0] = (__bf16)v[0]; pk[1] = (__bf16)v[1]; pk[2] = (__bf16)v[2]; pk[3] = (__bf16)v[3];
    *(bf16x4*)(&Xs[row * 264 + c4 * 4]) = pk;
  }
  __syncthreads();  // barrier 1: Xs staged

  // ---- half-batch weight loads: 4 coalesced 1KiB wave loads each ----
  bf16x8 bbA[4], bbB[4];
  auto load_qkv_h = [&](int c, int half, bf16x8* dst) {
    int hloc = wave * 2 + (c >= 12 ? 1 : 0);
    int r = (c >= 12) ? c - 12 : c;
    int mat = r >> 2, nt = r & 3;
    const __bf16* base = WqkvP + ((size_t)((mat * 8 + hloc) * 4 + nt)) * 4096 +
                         (size_t)half * 2048 + lane * 8;
#pragma unroll
    for (int kk = 0; kk < 4; kk++) dst[kk] = *(const bf16x8*)(base + kk * 512);
  };

  load_qkv_h(0, 0, bbA);
  load_qkv_h(0, 1, bbB);

  // ---- hoist X A-fragments (reused by all 24 qkv combos) ----
  bf16x8 xa0[8], xa1[8];
#pragma unroll
  for (int kk = 0; kk < 8; kk++) {
    xa0[kk] = *(const bf16x8*)(&Xs[l16 * 264 + kk * 32 + quad * 8]);
    xa1[kk] = *(const bf16x8*)(&Xs[(16 + l16) * 264 + kk * 32 + quad * 8]);
  }
  __syncthreads();  // barrier 1b: all waves done reading Xs before pool is overwritten

  const f32x4 zero = {0.f, 0.f, 0.f, 0.f};
  // qs/ks swizzle: logical (r,c) -> phys r*64 + (c&7) + (((c>>3) ^ (r&7)) << 3).
  const int A7 = l16 & 7;          // c&7 for write cols nt*16+l16; r&7 for read rows l16
  const int B1 = l16 >> 3;         // (c>>3) low bit from l16
  const int Q4 = (quad & 1) << 2;  // (r&7) contribution of write rows quad*4+rr
  // vT XOR-swizzle term: ((row>>1)&3)<<3 with row = nt*16+l16 == ((l16>>1)&3)<<3.
  const int vswz = ((l16 >> 1) & 3) << 3;
  bf16x4 obf[2][2][4];  // O output [hh][mt][nt] in regs until Os write

#pragma unroll
  for (int hh = 0; hh < 2; hh++) {
#pragma unroll
    for (int r = 0; r < 12; r++) {
      const int c = hh * 12 + r;
      const int mat = r >> 2, nt = r & 3;
      f32x4 a0 = zero, a1 = zero;
      // first K-half with bbA, then refill bbA for c+1 (ping-pong, dist = 1/2 step)
#pragma unroll
      for (int kk = 0; kk < 4; kk++) {
        a0 = mfma16(xa0[kk], bbA[kk], a0);
        a1 = mfma16(xa1[kk], bbA[kk], a1);
      }
      if (c + 1 < 24) load_qkv_h(c + 1, 0, bbA);
      // second K-half with bbB, then refill bbB for c+1
#pragma unroll
      for (int kk = 0; kk < 4; kk++) {
        a0 = mfma16(xa0[4 + kk], bbB[kk], a0);
        a1 = mfma16(xa1[4 + kk], bbB[kk], a1);
      }
      if (c + 1 < 24) load_qkv_h(c + 1, 1, bbB);

      if (mat == 0) {  // q — fold softmax scale 1/8
#pragma unroll
        for (int rr = 0; rr < 4; rr++) {
          int pc = A7 + (((nt * 2) ^ B1 ^ Q4 ^ rr) << 3);  // swizzled col
          qs[(quad * 4 + rr) * 64 + pc]      = (__bf16)(a0[rr] * 0.125f);
          qs[(16 + quad * 4 + rr) * 64 + pc] = (__bf16)(a1[rr] * 0.125f);
        }
      } else if (mat == 1) {
#pragma unroll
        for (int rr = 0; rr < 4; rr++) {
          int pc = A7 + (((nt * 2) ^ B1 ^ Q4 ^ rr) << 3);
          ks[(quad * 4 + rr) * 64 + pc]      = (__bf16)a0[rr];
          ks[(16 + quad * 4 + rr) * 64 + pc] = (__bf16)a1[rr];
        }
      } else {  // v transposed: vT[d][token], token cols XOR-swizzled by ((d>>1)&3)<<3
        bf16x4 p0, p1;
#pragma unroll
        for (int rr = 0; rr < 4; rr++) { p0[rr] = (__bf16)a0[rr]; p1[rr] = (__bf16)a1[rr]; }
        int rb = (nt * 16 + l16) * 32;
        *(bf16x4*)(&vT[rb + ((quad * 4) ^ vswz)])      = p0;
        *(bf16x4*)(&vT[rb + ((16 + quad * 4) ^ vswz)]) = p1;
      }
    }

    // ---- S = q @ k^T (scale folded into q), wave-private ----
    f32x4 s[2][2] = {{zero, zero}, {zero, zero}};
#pragma unroll
    for (int kk = 0; kk < 2; kk++) {
      int sl = ((kk * 4) ^ quad ^ A7) << 3;
      bf16x8 a0 = *(const bf16x8*)(&qs[l16 * 64 + sl]);
      bf16x8 a1 = *(const bf16x8*)(&qs[(16 + l16) * 64 + sl]);
      bf16x8 b0 = *(const bf16x8*)(&ks[l16 * 64 + sl]);
      bf16x8 b1 = *(const bf16x8*)(&ks[(16 + l16) * 64 + sl]);
      s[0][0] = mfma16(a0, b0, s[0][0]);
      s[0][1] = mfma16(a0, b1, s[0][1]);
      s[1][0] = mfma16(a1, b0, s[1][0]);
      s[1][1] = mfma16(a1, b1, s[1][1]);
    }

    // ---- in-register softmax: row i lives in the 16 lanes of one quad ----
    float mx[2][4], sm[2][4], e[2][2][4];
#pragma unroll
    for (int mt = 0; mt < 2; mt++)
#pragma unroll
      for (int rr = 0; rr < 4; rr++) mx[mt][rr] = fmaxf(s[mt][0][rr], s[mt][1][rr]);
#pragma unroll
    for (int mask = 1; mask < 16; mask <<= 1)
#pragma unroll
      for (int mt = 0; mt < 2; mt++)
#pragma unroll
        for (int rr = 0; rr < 4; rr++) mx[mt][rr] = fmaxf(mx[mt][rr], __shfl_xor(mx[mt][rr], mask));
#pragma unroll
    for (int mt = 0; mt < 2; mt++)
#pragma unroll
      for (int rr = 0; rr < 4; rr++) {
        e[mt][0][rr] = __expf(s[mt][0][rr] - mx[mt][rr]);
        e[mt][1][rr] = __expf(s[mt][1][rr] - mx[mt][rr]);
        sm[mt][rr] = e[mt][0][rr] + e[mt][1][rr];
      }
#pragma unroll
    for (int mask = 1; mask < 16; mask <<= 1)
#pragma unroll
      for (int mt = 0; mt < 2; mt++)
#pragma unroll
        for (int rr = 0; rr < 4; rr++) sm[mt][rr] += __shfl_xor(sm[mt][rr], mask);

    // ---- P -> LDS (C-layout, reuse qs; qs fully consumed above) -> reread in A-layout ----
#pragma unroll
    for (int mt = 0; mt < 2; mt++) {
      float inv0 = 1.f / sm[mt][0], inv1 = 1.f / sm[mt][1], inv2 = 1.f / sm[mt][2], inv3 = 1.f / sm[mt][3];
#pragma unroll
      for (int nt = 0; nt < 2; nt++) {
#pragma unroll
        for (int rr = 0; rr < 4; rr++) {
          int pc = A7 + (((nt * 2) ^ B1 ^ Q4 ^ rr) << 3);
          float inv = (rr == 0) ? inv0 : (rr == 1) ? inv1 : (rr == 2) ? inv2 : inv3;
          qs[(mt * 16 + quad * 4 + rr) * 64 + pc] = (__bf16)(e[mt][nt][rr] * inv);
        }
      }
    }
    bf16x8 pa0 = *(const bf16x8*)(&qs[l16 * 64 + ((quad ^ A7) << 3)]);
    bf16x8 pa1 = *(const bf16x8*)(&qs[(16 + l16) * 64 + ((quad ^ A7) << 3)]);

    // ---- O = P @ v ----
#pragma unroll
    for (int nt = 0; nt < 4; nt++) {
      bf16x8 b = *(const bf16x8*)(&vT[(nt * 16 + l16) * 32 + ((quad * 8) ^ vswz)]);
      f32x4 o0 = mfma16(pa0, b, zero);
      f32x4 o1 = mfma16(pa1, b, zero);
#pragma unroll
      for (int rr = 0; rr < 4; rr++) {
        obf[hh][0][nt][rr] = (__bf16)o0[rr];
        obf[hh][1][nt][rr] = (__bf16)o1[rr];
      }
    }
  }

  // ---- prefetch first out-proj half-batches before the barriers ----
  bf16x8 wbA[4], wbB[4];
  auto load_wout_h = [&](int b, int half, bf16x8* dst) {
    int g = b >> 1, ntile = wave + g * 4, kk0 = (b & 1) * 8 + half * 4;
    const __bf16* base = WoutP + ((size_t)(ntile * 16 + kk0) * 64 + lane) * 8;
#pragma unroll
    for (int j = 0; j < 4; j++) dst[j] = *(const bf16x8*)(base + j * 512);
  };
  load_wout_h(0, 0, wbA);
  load_wout_h(0, 1, wbB);

  __syncthreads();  // barrier 2: waves done with private pool regions

  // ---- write O (all heads) into Os[32][520] overlaying pool ----
#pragma unroll
  for (int hh = 0; hh < 2; hh++) {
    int h = wave * 2 + hh;
#pragma unroll
    for (int mt = 0; mt < 2; mt++)
#pragma unroll
      for (int nt = 0; nt < 4; nt++)
#pragma unroll
        for (int rr = 0; rr < 4; rr++)
          Os[(mt * 16 + quad * 4 + rr) * 520 + h * 64 + nt * 16 + l16] = obf[hh][mt][nt][rr];
  }
  __syncthreads();  // barrier 3

  // ---- out = O @ W_out + b : 8 weight batches, ping-pong half-buffers ----
  f32x4 outacc[4][2];
#pragma unroll
  for (int g = 0; g < 4; g++) { outacc[g][0] = zero; outacc[g][1] = zero; }
#pragma unroll
  for (int b = 0; b < 8; b++) {
    int g = b >> 1, kk0 = (b & 1) * 8;
#pragma unroll
    for (int j = 0; j < 4; j++) {
      int kk = kk0 + j;
      bf16x8 a0 = *(const bf16x8*)(&Os[l16 * 520 + kk * 32 + quad * 8]);
      bf16x8 a1 = *(const bf16x8*)(&Os[(16 + l16) * 520 + kk * 32 + quad * 8]);
      outacc[g][0] = mfma16(a0, wbA[j], outacc[g][0]);
      outacc[g][1] = mfma16(a1, wbA[j], outacc[g][1]);
    }
    if (b + 1 < 8) load_wout_h(b + 1, 0, wbA);
#pragma unroll
    for (int j = 0; j < 4; j++) {
      int kk = kk0 + 4 + j;
      bf16x8 a0 = *(const bf16x8*)(&Os[l16 * 520 + kk * 32 + quad * 8]);
      bf16x8 a1 = *(const bf16x8*)(&Os[(16 + l16) * 520 + kk * 32 + quad * 8]);
      outacc[g][0] = mfma16(a0, wbB[j], outacc[g][0]);
      outacc[g][1] = mfma16(a1, wbB[j], outacc[g][1]);
    }
    if (b + 1 < 8) load_wout_h(b + 1, 1, wbB);
  }

  // ---- epilogue: bias + store (plain stores: let L2 merge 64B half-lines) ----
  float* og = out + (size_t)bp * 32 * 256;
#pragma unroll
  for (int g = 0; g < 4; g++) {
    int ntile = wave + g * 4;
    float bias = b_out[ntile * 16 + l16];
#pragma unroll
    for (int mt = 0; mt < 2; mt++) {
      f32x4 a = outacc[g][mt];
#pragma unroll
      for (int rr = 0; rr < 4; rr++)
        og[(mt * 16 + quad * 4 + rr) * 256 + ntile * 16 + l16] = a[rr] + bias;
    }
  }
}

extern "C" void kernel_launch(void* const* d_in, const int* in_sizes, int n_in,
                              void* d_out, int out_size, void* d_ws, size_t ws_size,
                              hipStream_t stream) {
  const float* x    = (const float*)d_in[0];
  const float* Wqkv = (const float*)d_in[1];
  const float* Wout = (const float*)d_in[2];
  const float* bout = (const float*)d_in[3];
  float* out = (float*)d_out;

  __bf16* WqkvP = (__bf16*)d_ws;
  __bf16* WoutP = (__bf16*)((char*)d_ws + (size_t)1536 * 256 * 2);

  prep_weights<<<256, 256, 0, stream>>>(Wqkv, Wout, WqkvP, WoutP);
  attn_fused<<<4096, 256, 0, stream>>>(x, WqkvP, WoutP, bout, out);
}

// Round 8
// 392.067 us; speedup vs baseline: 1.2151x; 1.2151x over previous
//
#include <hip/hip_runtime.h>

// Attention_37074157699274 : fused qkv-proj + 8-head attention (n=32,d=64) + out-proj
// R3: fragment-packed weights, dist-2 weight prefetch, nt x-streaming.
// R4-R7: LDS 74240->49152 (Xs/Os overlay pool, vT [64][32]+swz, qs/ks [32][64]+swz).
// R5/R10: __launch_bounds__(256,3) achieved 32% occupancy BOTH times but spilled
//   (972MB / 414MB scratch writes) — structure needs ~200+ live regs vs 168 budget.
//   3-wave path abandoned; stay at (256,2), 2 waves/SIMD, zero spill.
// R11: attack per-wave MFMA dependence instead. QKV ran 2 dependent chains of 8
//   MFMAs (a0,a1 over kk); dep-latency ~17cyc vs ~5cyc issue => wave self-caps the
//   matrix pipe. Split-K: even/odd-kk accumulators (4 chains of 4) in QKV, j-parity
//   split in out-proj. +40 VGPRs, fits 2-wave budget. MFMA floor is 70us (146 GF @
//   2075 TF); target MfmaUtil 25->32-40%.

typedef __bf16 bf16x8 __attribute__((ext_vector_type(8)));
typedef __bf16 bf16x4 __attribute__((ext_vector_type(4)));
typedef float f32x4 __attribute__((ext_vector_type(4)));
typedef float f32x4v __attribute__((ext_vector_type(4)));

__device__ __forceinline__ f32x4 mfma16(bf16x8 a, bf16x8 b, f32x4 c) {
  return __builtin_amdgcn_mfma_f32_16x16x32_bf16(a, b, c, 0, 0, 0);
}

// ws: [0,786432) WqkvP bf16 packed frags ; [786432,1048576) WoutP bf16 packed frags
// WqkvP: frag t = (combo*8 + kk)*64 + lane, combo = (mat*8+h)*4+nt, 8 ele each:
//   ele j = Wqkv[k][n], n = mat*512+h*64+nt*16+(lane&15), k = kk*32+(lane>>4)*8+j
// WoutP: frag t = (ntile*16 + kk)*64 + lane:
//   ele j = Wout[k][n], n = ntile*16+(lane&15), k = kk*32+(lane>>4)*8+j
__global__ __launch_bounds__(256) void prep_weights(const float* __restrict__ Wqkv,
                                                    const float* __restrict__ Wout,
                                                    __bf16* __restrict__ WqkvP,
                                                    __bf16* __restrict__ WoutP) {
  int t = blockIdx.x * 256 + threadIdx.x;
  if (t < 49152) {
    int lane = t & 63, rest = t >> 6;
    int kk = rest & 7, combo = rest >> 3;
    int nt = combo & 3, mh = combo >> 2;
    int h = mh & 7, mat = mh >> 3;
    int l16 = lane & 15, quad = lane >> 4;
    int n = mat * 512 + h * 64 + nt * 16 + l16;
    int k0 = kk * 32 + quad * 8;
    __bf16* dst = WqkvP + (size_t)t * 8;
#pragma unroll
    for (int j = 0; j < 8; j++) dst[j] = (__bf16)Wqkv[(size_t)(k0 + j) * 1536 + n];
  }
  int t2 = t - 49152;
  if (t2 >= 0 && t2 < 16384) {
    int lane = t2 & 63, rest = t2 >> 6;
    int kk = rest & 15, ntile = rest >> 4;
    int l16 = lane & 15, quad = lane >> 4;
    int n = ntile * 16 + l16;
    int k0 = kk * 32 + quad * 8;
    __bf16* dst = WoutP + (size_t)t2 * 8;
#pragma unroll
    for (int j = 0; j < 8; j++) dst[j] = (__bf16)Wout[(size_t)(k0 + j) * 256 + n];
  }
}

__global__ __launch_bounds__(256, 2) void attn_fused(const float* __restrict__ x,
                                                     const __bf16* __restrict__ WqkvP,
                                                     const __bf16* __restrict__ WoutP,
                                                     const float* __restrict__ b_out,
                                                     float* __restrict__ out) {
  // Single pool, 49152 B. 2 blocks/CU (register-bound; accepted per R5/R10).
  // Phase A (staging):   Xs overlay [32][264] = 8448 ele
  // Phase B (attention): per-wave {qs[32][64] swz, ks[32][64] swz, vT[64][32] swz} = 6144 ele
  // Phase C (out-proj):  Os overlay [32][520] = 16640 ele
  __shared__ __align__(16) __bf16 pool[4 * 6144];

  const int tid  = threadIdx.x;
  const int wave = tid >> 6;
  const int lane = tid & 63;
  const int quad = lane >> 4;
  const int l16  = lane & 15;
  const int bp   = blockIdx.x;

  __bf16* qs = pool + wave * 6144;  // [32][64] swizzled (reused as P scratch)
  __bf16* ks = qs + 2048;           // [32][64] swizzled
  __bf16* vT = ks + 2048;           // [64][32] v transposed, XOR-swizzled
  __bf16* Xs = pool;                // [32][264] staging overlay (dead after hoist)
  __bf16* Os = pool;                // [32][520] after barrier 2 (overlays pool)

  // ---- stage X tile -> LDS bf16 (non-temporal: read-once stream) ----
  const f32x4v* xg = (const f32x4v*)(x + (size_t)bp * 32 * 256);
  for (int i = tid; i < 32 * 64; i += 256) {
    int row = i >> 6, c4 = i & 63;
    f32x4v v = __builtin_nontemporal_load(xg + i);
    bf16x4 pk;
    pk[0] = (__bf16)v[0]; pk[1] = (__bf16)v[1]; pk[2] = (__bf16)v[2]; pk[3] = (__bf16)v[3];
    *(bf16x4*)(&Xs[row * 264 + c4 * 4]) = pk;
  }
  __syncthreads();  // barrier 1: Xs staged

  // ---- weight-fragment load helpers (each: 8 perfectly-coalesced 1KiB wave loads) ----
  bf16x8 bb[2][8];
  auto load_qkv = [&](int c, bf16x8* dst) {
    int hloc = wave * 2 + (c >= 12 ? 1 : 0);
    int r = (c >= 12) ? c - 12 : c;
    int mat = r >> 2, nt = r & 3;
    const __bf16* base = WqkvP + ((size_t)((mat * 8 + hloc) * 4 + nt)) * 4096 + lane * 8;
#pragma unroll
    for (int kk = 0; kk < 8; kk++) dst[kk] = *(const bf16x8*)(base + kk * 512);
  };

  load_qkv(0, bb[0]);
  load_qkv(1, bb[1]);

  // ---- hoist X A-fragments (reused by all 24 qkv combos) ----
  bf16x8 xa0[8], xa1[8];
#pragma unroll
  for (int kk = 0; kk < 8; kk++) {
    xa0[kk] = *(const bf16x8*)(&Xs[l16 * 264 + kk * 32 + quad * 8]);
    xa1[kk] = *(const bf16x8*)(&Xs[(16 + l16) * 264 + kk * 32 + quad * 8]);
  }
  __syncthreads();  // barrier 1b: all waves done reading Xs before pool is overwritten

  const f32x4 zero = {0.f, 0.f, 0.f, 0.f};
  // qs/ks swizzle: logical (r,c) -> phys r*64 + (c&7) + (((c>>3) ^ (r&7)) << 3).
  const int A7 = l16 & 7;          // c&7 for write cols nt*16+l16; r&7 for read rows l16
  const int B1 = l16 >> 3;         // (c>>3) low bit from l16
  const int Q4 = (quad & 1) << 2;  // (r&7) contribution of write rows quad*4+rr
  // vT XOR-swizzle term: ((row>>1)&3)<<3 with row = nt*16+l16 == ((l16>>1)&3)<<3.
  const int vswz = ((l16 >> 1) & 3) << 3;
  bf16x4 obf[2][2][4];  // O output [hh][mt][nt] in regs until Os write

#pragma unroll
  for (int hh = 0; hh < 2; hh++) {
#pragma unroll
    for (int r = 0; r < 12; r++) {
      const int c = hh * 12 + r;
      const int mat = r >> 2, nt = r & 3;
      // split-K: 4 independent accumulation chains of 4 (even/odd kk x two M-tiles)
      f32x4 a0e = zero, a0o = zero, a1e = zero, a1o = zero;
#pragma unroll
      for (int kk = 0; kk < 4; kk++) {
        a0e = mfma16(xa0[2 * kk],     bb[c & 1][2 * kk],     a0e);
        a0o = mfma16(xa0[2 * kk + 1], bb[c & 1][2 * kk + 1], a0o);
        a1e = mfma16(xa1[2 * kk],     bb[c & 1][2 * kk],     a1e);
        a1o = mfma16(xa1[2 * kk + 1], bb[c & 1][2 * kk + 1], a1o);
      }
      if (c + 2 < 24) load_qkv(c + 2, bb[c & 1]);  // distance-2 prefetch (after last use)
      f32x4 a0 = a0e + a0o;
      f32x4 a1 = a1e + a1o;
      if (mat == 0) {  // q — fold softmax scale 1/8
#pragma unroll
        for (int rr = 0; rr < 4; rr++) {
          int pc = A7 + (((nt * 2) ^ B1 ^ Q4 ^ rr) << 3);  // swizzled col
          qs[(quad * 4 + rr) * 64 + pc]      = (__bf16)(a0[rr] * 0.125f);
          qs[(16 + quad * 4 + rr) * 64 + pc] = (__bf16)(a1[rr] * 0.125f);
        }
      } else if (mat == 1) {
#pragma unroll
        for (int rr = 0; rr < 4; rr++) {
          int pc = A7 + (((nt * 2) ^ B1 ^ Q4 ^ rr) << 3);
          ks[(quad * 4 + rr) * 64 + pc]      = (__bf16)a0[rr];
          ks[(16 + quad * 4 + rr) * 64 + pc] = (__bf16)a1[rr];
        }
      } else {  // v transposed: vT[d][token], token cols XOR-swizzled by ((d>>1)&3)<<3
        bf16x4 p0, p1;
#pragma unroll
        for (int rr = 0; rr < 4; rr++) { p0[rr] = (__bf16)a0[rr]; p1[rr] = (__bf16)a1[rr]; }
        int rb = (nt * 16 + l16) * 32;
        *(bf16x4*)(&vT[rb + ((quad * 4) ^ vswz)])      = p0;
        *(bf16x4*)(&vT[rb + ((16 + quad * 4) ^ vswz)]) = p1;
      }
    }

    // ---- S = q @ k^T (scale folded into q), wave-private ----
    f32x4 s[2][2] = {{zero, zero}, {zero, zero}};
#pragma unroll
    for (int kk = 0; kk < 2; kk++) {
      int sl = ((kk * 4) ^ quad ^ A7) << 3;
      bf16x8 a0 = *(const bf16x8*)(&qs[l16 * 64 + sl]);
      bf16x8 a1 = *(const bf16x8*)(&qs[(16 + l16) * 64 + sl]);
      bf16x8 b0 = *(const bf16x8*)(&ks[l16 * 64 + sl]);
      bf16x8 b1 = *(const bf16x8*)(&ks[(16 + l16) * 64 + sl]);
      s[0][0] = mfma16(a0, b0, s[0][0]);
      s[0][1] = mfma16(a0, b1, s[0][1]);
      s[1][0] = mfma16(a1, b0, s[1][0]);
      s[1][1] = mfma16(a1, b1, s[1][1]);
    }

    // ---- in-register softmax: row i lives in the 16 lanes of one quad ----
    float mx[2][4], sm[2][4], e[2][2][4];
#pragma unroll
    for (int mt = 0; mt < 2; mt++)
#pragma unroll
      for (int rr = 0; rr < 4; rr++) mx[mt][rr] = fmaxf(s[mt][0][rr], s[mt][1][rr]);
#pragma unroll
    for (int mask = 1; mask < 16; mask <<= 1)
#pragma unroll
      for (int mt = 0; mt < 2; mt++)
#pragma unroll
        for (int rr = 0; rr < 4; rr++) mx[mt][rr] = fmaxf(mx[mt][rr], __shfl_xor(mx[mt][rr], mask));
#pragma unroll
    for (int mt = 0; mt < 2; mt++)
#pragma unroll
      for (int rr = 0; rr < 4; rr++) {
        e[mt][0][rr] = __expf(s[mt][0][rr] - mx[mt][rr]);
        e[mt][1][rr] = __expf(s[mt][1][rr] - mx[mt][rr]);
        sm[mt][rr] = e[mt][0][rr] + e[mt][1][rr];
      }
#pragma unroll
    for (int mask = 1; mask < 16; mask <<= 1)
#pragma unroll
      for (int mt = 0; mt < 2; mt++)
#pragma unroll
        for (int rr = 0; rr < 4; rr++) sm[mt][rr] += __shfl_xor(sm[mt][rr], mask);

    // ---- P -> LDS (C-layout, reuse qs; qs fully consumed above) -> reread in A-layout ----
#pragma unroll
    for (int mt = 0; mt < 2; mt++) {
      float inv0 = 1.f / sm[mt][0], inv1 = 1.f / sm[mt][1], inv2 = 1.f / sm[mt][2], inv3 = 1.f / sm[mt][3];
#pragma unroll
      for (int nt = 0; nt < 2; nt++) {
#pragma unroll
        for (int rr = 0; rr < 4; rr++) {
          int pc = A7 + (((nt * 2) ^ B1 ^ Q4 ^ rr) << 3);
          float inv = (rr == 0) ? inv0 : (rr == 1) ? inv1 : (rr == 2) ? inv2 : inv3;
          qs[(mt * 16 + quad * 4 + rr) * 64 + pc] = (__bf16)(e[mt][nt][rr] * inv);
        }
      }
    }
    bf16x8 pa0 = *(const bf16x8*)(&qs[l16 * 64 + ((quad ^ A7) << 3)]);
    bf16x8 pa1 = *(const bf16x8*)(&qs[(16 + l16) * 64 + ((quad ^ A7) << 3)]);

    // ---- O = P @ v ----
#pragma unroll
    for (int nt = 0; nt < 4; nt++) {
      bf16x8 b = *(const bf16x8*)(&vT[(nt * 16 + l16) * 32 + ((quad * 8) ^ vswz)]);
      f32x4 o0 = mfma16(pa0, b, zero);
      f32x4 o1 = mfma16(pa1, b, zero);
#pragma unroll
      for (int rr = 0; rr < 4; rr++) {
        obf[hh][0][nt][rr] = (__bf16)o0[rr];
        obf[hh][1][nt][rr] = (__bf16)o1[rr];
      }
    }
  }

  // ---- prefetch first two out-proj weight batches before the barriers ----
  bf16x8 wb[2][8];
  auto load_wout = [&](int b, bf16x8* dst) {
    int g = b >> 1, ntile = wave + g * 4, kk0 = (b & 1) * 8;
    const __bf16* base = WoutP + ((size_t)(ntile * 16 + kk0) * 64 + lane) * 8;
#pragma unroll
    for (int j = 0; j < 8; j++) dst[j] = *(const bf16x8*)(base + j * 512);
  };
  load_wout(0, wb[0]);
  load_wout(1, wb[1]);

  __syncthreads();  // barrier 2: waves done with private pool regions

  // ---- write O (all heads) into Os[32][520] overlaying pool ----
#pragma unroll
  for (int hh = 0; hh < 2; hh++) {
    int h = wave * 2 + hh;
#pragma unroll
    for (int mt = 0; mt < 2; mt++)
#pragma unroll
      for (int nt = 0; nt < 4; nt++)
#pragma unroll
        for (int rr = 0; rr < 4; rr++)
          Os[(mt * 16 + quad * 4 + rr) * 520 + h * 64 + nt * 16 + l16] = obf[hh][mt][nt][rr];
  }
  __syncthreads();  // barrier 3

  // ---- out = O @ W_out + b : 8 pipelined weight batches, j-parity split chains ----
  f32x4 outacc[4][2], outacc2[4][2];
#pragma unroll
  for (int g = 0; g < 4; g++) {
    outacc[g][0] = zero; outacc[g][1] = zero;
    outacc2[g][0] = zero; outacc2[g][1] = zero;
  }
#pragma unroll
  for (int b = 0; b < 8; b++) {
    int g = b >> 1, kk0 = (b & 1) * 8;
#pragma unroll
    for (int j = 0; j < 4; j++) {
      int kkE = kk0 + 2 * j, kkO = kk0 + 2 * j + 1;
      bf16x8 aE0 = *(const bf16x8*)(&Os[l16 * 520 + kkE * 32 + quad * 8]);
      bf16x8 aE1 = *(const bf16x8*)(&Os[(16 + l16) * 520 + kkE * 32 + quad * 8]);
      bf16x8 aO0 = *(const bf16x8*)(&Os[l16 * 520 + kkO * 32 + quad * 8]);
      bf16x8 aO1 = *(const bf16x8*)(&Os[(16 + l16) * 520 + kkO * 32 + quad * 8]);
      outacc[g][0]  = mfma16(aE0, wb[b & 1][2 * j],     outacc[g][0]);
      outacc2[g][0] = mfma16(aO0, wb[b & 1][2 * j + 1], outacc2[g][0]);
      outacc[g][1]  = mfma16(aE1, wb[b & 1][2 * j],     outacc[g][1]);
      outacc2[g][1] = mfma16(aO1, wb[b & 1][2 * j + 1], outacc2[g][1]);
    }
    if (b + 2 < 8) load_wout(b + 2, wb[b & 1]);  // distance-2, after last use
  }

  // ---- epilogue: bias + store (plain stores: let L2 merge 64B half-lines) ----
  float* og = out + (size_t)bp * 32 * 256;
#pragma unroll
  for (int g = 0; g < 4; g++) {
    int ntile = wave + g * 4;
    float bias = b_out[ntile * 16 + l16];
#pragma unroll
    for (int mt = 0; mt < 2; mt++) {
      f32x4 a = outacc[g][mt] + outacc2[g][mt];
#pragma unroll
      for (int rr = 0; rr < 4; rr++)
        og[(mt * 16 + quad * 4 + rr) * 256 + ntile * 16 + l16] = a[rr] + bias;
    }
  }
}

extern "C" void kernel_launch(void* const* d_in, const int* in_sizes, int n_in,
                              void* d_out, int out_size, void* d_ws, size_t ws_size,
                              hipStream_t stream) {
  const float* x    = (const float*)d_in[0];
  const float* Wqkv = (const float*)d_in[1];
  const float* Wout = (const float*)d_in[2];
  const float* bout = (const float*)d_in[3];
  float* out = (float*)d_out;

  __bf16* WqkvP = (__bf16*)d_ws;
  __bf16* WoutP = (__bf16*)((char*)d_ws + (size_t)1536 * 256 * 2);

  prep_weights<<<256, 256, 0, stream>>>(Wqkv, Wout, WqkvP, WoutP);
  attn_fused<<<4096, 256, 0, stream>>>(x, WqkvP, WoutP, bout, out);
}